// Round 10
// baseline (44.645 us; speedup 1.0000x reference)
//
#include <hip/hip_runtime.h>

#define NN 512
#define DD 9
#define LL 32
#define NT 32   // 16x16 tiles per dimension

typedef _Float16 f16x8 __attribute__((ext_vector_type(8)));
typedef float    f32x4 __attribute__((ext_vector_type(4)));
typedef unsigned long long u64;

__device__ __forceinline__ u64 umin64(u64 a, u64 b) { return a < b ? a : b; }

// Scan: pass-local wave wp owns 4 row-tiles {4wp..4wp+3} of the "a side",
// scans all 32 "b side" tiles. B-fragment is register double-buffered: the
// ds_read_b128 for jj+1 issues before jj's MFMAs/compares, hiding LDS latency.
// MFMA emits the complete distance (cross hi/lo split k0..15, norms k16..19).
// Tracking: cmp + dual-cndmask on raw d, ascending col -> first index. One
// xor-8 butterfly merges 16 col-groups to 8; active lanes write u64 lex keys
// (clamped dbits<<32)|col to part[row][group].
__device__ __forceinline__ void min_scan4(const f16x8* __restrict__ sAs,
                                          const f16x8* __restrict__ sBs,
                                          u64 (* __restrict__ part)[9],
                                          int wp, int lane)
{
    const int ti0 = wp * 4;
    f16x8 afr[4];
    #pragma unroll
    for (int q = 0; q < 4; ++q) afr[q] = sAs[(ti0 + q) * 64 + lane];

    float    bd[16];
    unsigned bc[16];
    #pragma unroll
    for (int i = 0; i < 16; ++i) { bd[i] = 1e30f; bc[i] = 0; }

    const f32x4 zero = {0.f, 0.f, 0.f, 0.f};
    unsigned colg = (unsigned)(lane & 15);

    f16x8 bfr = sBs[lane];   // prefetch jj=0
    #pragma unroll 2
    for (int jj = 0; jj < NT; ++jj) {
        f16x8 cur = bfr;
        if (jj < NT - 1) bfr = sBs[(jj + 1) * 64 + lane];   // issue next read early
        #pragma unroll
        for (int q = 0; q < 4; ++q) {
            f32x4 d4 = __builtin_amdgcn_mfma_f32_16x16x32_f16(afr[q], cur, zero, 0, 0, 0);
            #pragma unroll
            for (int r = 0; r < 4; ++r) {
                if (d4[r] < bd[q * 4 + r]) { bd[q * 4 + r] = d4[r]; bc[q * 4 + r] = colg; }
            }
        }
        colg += 16;
    }

    // one butterfly step: merge col-groups g and g+8 (exact lex on (d, col))
    #pragma unroll
    for (int i = 0; i < 16; ++i) {
        float    pd = __shfl_xor(bd[i], 8, 64);
        unsigned pc = (unsigned)__shfl_xor((int)bc[i], 8, 64);
        bool take = (pd < bd[i]) || (pd == bd[i] && pc < bc[i]);
        bd[i] = take ? pd : bd[i];
        bc[i] = take ? pc : bc[i];
    }
    if ((lane & 8) == 0) {
        const int g  = lane & 7;
        const int rb = ((lane >> 4) << 2);
        #pragma unroll
        for (int q = 0; q < 4; ++q) {
            #pragma unroll
            for (int r = 0; r < 4; ++r) {
                const int row = (ti0 + q) * 16 + rb + r;
                const float dc = fmaxf(bd[q * 4 + r], 0.f);   // clamp at pack (ref semantics)
                part[row][g] = (((u64)__float_as_uint(dc)) << 32) | (u64)bc[q * 4 + r];
            }
        }
    }
}

// One block per batch, 1024 threads = 16 waves. Waves 0-7: pass 1 (input rows
// vs pred cols); waves 8-15: pass 2 operand-swapped.
__global__ __launch_bounds__(1024, 8)
void loss_kernel(const float* __restrict__ kine_input,
                 const float* __restrict__ class_input,
                 const float* __restrict__ kine_pred,
                 const float* __restrict__ class_pred,
                 const float* __restrict__ mu,
                 const float* __restrict__ log_var,
                 float* __restrict__ out)
{
    const int b    = (int)blockIdx.x;
    const int t    = (int)threadIdx.x;
    const int lane = t & 63;
    const int wave = t >> 6;

    __shared__ f16x8 sA[NT * 64];        // A' fragments (input side), 32 KB
    __shared__ f16x8 sB[NT * 64];        // B' fragments (pred side),  32 KB
    __shared__ u64   part[2][NN][9];     // lex-key partials, 72 KB
    __shared__ float red[16];
    __shared__ float s_kl;
    __shared__ int   hist_in[DD], hist_pr[DD];

    if (t < DD) { hist_in[t] = 0; hist_pr[t] = 0; }

    // ---- hoisted epilogue operands: own class row (address known at entry) ----
    const int ep_p  = t >> 9;
    const int ep_lr = t & (NN - 1);
    const float* own = (ep_p ? class_pred : class_input) + ((size_t)b * NN + ep_lr) * DD;
    float ownv[DD];
    #pragma unroll
    for (int d2 = 0; d2 < DD; ++d2) ownv[d2] = own[d2];

    // ---- stage fragments: slot s = rep*1024+t -> side|ti|lane ----
    // lane ln: row/col = ti*16 + (ln&15), kg = ln>>4, k = kg*8+e.
    // k0..15 cross: A kg0=hi(-2x) kg1=lo(-2x); B e<4=hi(y) else lo(y).
    // k16..19 norms: (A,B) = (1,y2hi),(1,y2lo),(x2hi,1),(x2lo,1).
    #pragma unroll
    for (int rep = 0; rep < 4; ++rep) {
        const int s    = rep * 1024 + t;
        const int side = s >> 11;
        const int ti   = (s >> 6) & 31;
        const int ln   = s & 63;
        const int row  = ti * 16 + (ln & 15);
        const int kg   = ln >> 4;
        const float* P = side ? kine_pred : kine_input;
        float4 pt = *reinterpret_cast<const float4*>(P + ((size_t)b * NN + row) * 4);
        float n = pt.x*pt.x + pt.y*pt.y + pt.z*pt.z + pt.w*pt.w;
        float w[4];
        if (side == 0) { w[0] = -2.f*pt.x; w[1] = -2.f*pt.y; w[2] = -2.f*pt.z; w[3] = -2.f*pt.w; }
        else           { w[0] =      pt.x; w[1] =      pt.y; w[2] =      pt.z; w[3] =      pt.w; }
        _Float16 hi[4], lo[4];
        #pragma unroll
        for (int c = 0; c < 4; ++c) { hi[c] = (_Float16)w[c]; lo[c] = (_Float16)(w[c] - (float)hi[c]); }
        const _Float16 nhi = (_Float16)n;
        const _Float16 nlo = (_Float16)(n - (float)nhi);
        const _Float16 one = (_Float16)1.f;
        f16x8 hv;
        #pragma unroll
        for (int e = 0; e < 8; ++e) {
            _Float16 v = (_Float16)0.f;
            if (kg < 2) {
                const int c = e & 3;
                if (side == 0) v = (kg == 0) ? hi[c] : lo[c];
                else           v = (e < 4) ? hi[c] : lo[c];
            } else if (kg == 2 && e < 4) {
                if (side == 0) v = (e == 0 || e == 1) ? one : ((e == 2) ? nhi : nlo);
                else           v = (e == 0) ? nhi : ((e == 1) ? nlo : one);
            }
            hv[e] = v;
        }
        (side ? sB : sA)[ti * 64 + ln] = hv;
    }
    __syncthreads();

    // ---- concurrent transposed scans on wave halves ----
    if (wave < 8) min_scan4(sA, sB, part[0], wave,     lane);
    else          min_scan4(sB, sA, part[1], wave - 8, lane);

    // ---- histograms (labels independent of argmins) + KL ----
    {
        const float* cls = (t < NN) ? class_input : class_pred;
        const int r = t & (NN - 1);
        const float* rowp = cls + ((size_t)b * NN + r) * DD;
        float mx = rowp[0]; int lab = 0;
        #pragma unroll
        for (int d2 = 1; d2 < DD; ++d2) { float v = rowp[d2]; if (v > mx) { mx = v; lab = d2; } }  // argmax(exp)==argmax
        atomicAdd((t < NN) ? &hist_in[lab] : &hist_pr[lab], 1);
    }
    if (t < 64) {
        float v = 0.f;
        if (t < LL) {
            float m_ = mu[(size_t)b * LL + t];
            float lv = log_var[(size_t)b * LL + t];
            v = 1.f + lv - m_ * m_ - expf(lv);
        }
        #pragma unroll
        for (int off = 32; off > 0; off >>= 1) v += __shfl_down(v, off, 64);
        if (t == 0) s_kl = -0.5f * v;
    }
    __syncthreads();

    // ---- merge 8 groups + epilogue: thread t -> (pass ep_p, row ep_lr) ----
    float partsum;
    {
        u64 e = part[ep_p][ep_lr][0];
        #pragma unroll
        for (int g = 1; g < 8; ++g) e = umin64(e, part[ep_p][ep_lr][g]);
        const int   idx  = (int)(unsigned)(e & 0xFFFFFFFFull);
        const float dmin = __uint_as_float((unsigned)(e >> 32));
        const float* oth = (ep_p ? class_input : class_pred) + ((size_t)b * NN + idx) * DD;
        float dot = 0.f;
        #pragma unroll
        for (int d2 = 0; d2 < DD; ++d2) dot += ownv[d2] * oth[d2];
        partsum = dmin - dot;   // chamfer + (-1)*class dot (W=1)
    }
    #pragma unroll
    for (int off = 32; off > 0; off >>= 1) partsum += __shfl_down(partsum, off, 64);
    if (lane == 0) red[wave] = partsum;
    __syncthreads();

    if (t == 0) {
        float sum = 0.f;
        #pragma unroll
        for (int w2 = 0; w2 < 16; ++w2) sum += red[w2];
        float cnum = 0.f;
        #pragma unroll
        for (int c = 0; c < DD; ++c) {
            float diff = fabsf((float)(hist_pr[c] - hist_in[c]));
            float wgt = (c == 0) ? 2.0f : ((c == DD - 1) ? 100.0f : 1.0f);
            cnum += wgt * diff;
        }
        out[b] = 0.99f * (sum + 0.001f * cnum) + 0.01f * s_kl;
    }
}

extern "C" void kernel_launch(void* const* d_in, const int* in_sizes, int n_in,
                              void* d_out, int out_size, void* d_ws, size_t ws_size,
                              hipStream_t stream) {
    const float* kine_input  = (const float*)d_in[0];
    const float* class_input = (const float*)d_in[1];
    const float* kine_pred   = (const float*)d_in[2];
    const float* class_pred  = (const float*)d_in[3];
    const float* mu          = (const float*)d_in[4];
    const float* log_var     = (const float*)d_in[5];
    float* out = (float*)d_out;

    // DIAGNOSTIC ROUND: launch twice (bit-identical deterministic output; plain
    // final stores) so the kernel surfaces above the harness's 40us poison
    // fills in the rocprof top-5 and we recover counter visibility.
    // Real per-launch time = dur_us / 2.
    loss_kernel<<<256, 1024, 0, stream>>>(kine_input, class_input, kine_pred,
                                          class_pred, mu, log_var, out);
    loss_kernel<<<256, 1024, 0, stream>>>(kine_input, class_input, kine_pred,
                                          class_pred, mu, log_var, out);
}

// Round 11
// 21.501 us; speedup vs baseline: 2.0764x; 2.0764x over previous
//
#include <hip/hip_runtime.h>

#define NN 512
#define DD 9
#define LL 32
#define NT 32   // 16x16 tiles per dimension
#define PG 17   // part row stride (u32): odd -> conflict-free epilogue reads

typedef _Float16 f16x8 __attribute__((ext_vector_type(8)));
typedef float    f32x4 __attribute__((ext_vector_type(4)));

// Scan: pass-local wave wp owns 4 row-tiles {4wp..4wp+3} of the "a side",
// scans all 32 "b side" tiles (B register double-buffered). MFMA emits the
// complete distance (cross hi/lo split k0..15, norms folded k16..19).
// Tracking: pk = bfi(~31, dbits, jj); v_min_f32 accumulate = 2 VALU/cell.
// Within a lane (d_trunc, jj) min == first-index argmin over its col set
// col = (lane&15) + 16*jj. No cross-lane merge here: lane writes its packed
// min for (row, g=lane&15) to part[row][g]; epilogue re-attaches g.
__device__ __forceinline__ void min_scan4(const f16x8* __restrict__ sAs,
                                          const f16x8* __restrict__ sBs,
                                          unsigned (* __restrict__ part)[PG],
                                          int wp, int lane)
{
    const int ti0 = wp * 4;
    f16x8 afr[4];
    #pragma unroll
    for (int q = 0; q < 4; ++q) afr[q] = sAs[(ti0 + q) * 64 + lane];

    float bm[16];
    #pragma unroll
    for (int i = 0; i < 16; ++i) bm[i] = 1e30f;

    const f32x4 zero = {0.f, 0.f, 0.f, 0.f};

    f16x8 bfr = sBs[lane];   // prefetch jj=0
    #pragma unroll 2
    for (int jj = 0; jj < NT; ++jj) {
        f16x8 cur = bfr;
        if (jj < NT - 1) bfr = sBs[(jj + 1) * 64 + lane];   // issue next read early
        #pragma unroll
        for (int q = 0; q < 4; ++q) {
            f32x4 d4 = __builtin_amdgcn_mfma_f32_16x16x32_f16(afr[q], cur, zero, 0, 0, 0);
            #pragma unroll
            for (int r = 0; r < 4; ++r) {
                // (dbits & ~31) | (jj & 31)  ->  v_bfi_b32
                unsigned pk = (__float_as_uint(d4[r]) & 0xFFFFFFE0u) | ((unsigned)jj & 0x1Fu);
                bm[q * 4 + r] = fminf(bm[q * 4 + r], __uint_as_float(pk));
            }
        }
    }

    const int g  = lane & 15;
    const int rb = (lane >> 4) << 2;
    #pragma unroll
    for (int q = 0; q < 4; ++q) {
        #pragma unroll
        for (int r = 0; r < 4; ++r) {
            const int row = (ti0 + q) * 16 + rb + r;
            part[row][g] = __float_as_uint(bm[q * 4 + r]);
        }
    }
}

// One block per batch, 1024 threads = 16 waves. Waves 0-7: pass 1 (input rows
// vs pred cols); waves 8-15: pass 2 operand-swapped (valid: hi/lo pairing
// covers {hi,lo}^2 once in both roles; norm slots symmetric by construction).
__global__ __launch_bounds__(1024, 4)
void loss_kernel(const float* __restrict__ kine_input,
                 const float* __restrict__ class_input,
                 const float* __restrict__ kine_pred,
                 const float* __restrict__ class_pred,
                 const float* __restrict__ mu,
                 const float* __restrict__ log_var,
                 float* __restrict__ out)
{
    const int b    = (int)blockIdx.x;
    const int t    = (int)threadIdx.x;
    const int lane = t & 63;
    const int wave = t >> 6;

    __shared__ f16x8    sA[NT * 64];       // A' fragments (input side), 32 KB
    __shared__ f16x8    sB[NT * 64];       // B' fragments (pred side),  32 KB
    __shared__ unsigned part[2][NN][PG];   // packed per-(row, lane-group) minima, ~68 KB
    __shared__ float    red[16];
    __shared__ float    s_kl;
    __shared__ int      hist_in[DD], hist_pr[DD];

    if (t < DD) { hist_in[t] = 0; hist_pr[t] = 0; }

    // ---- hoisted epilogue operand: own class row (address known at entry) ----
    const int ep_p  = t >> 9;
    const int ep_lr = t & (NN - 1);
    const float* own = (ep_p ? class_pred : class_input) + ((size_t)b * NN + ep_lr) * DD;
    float ownv[DD];
    #pragma unroll
    for (int d2 = 0; d2 < DD; ++d2) ownv[d2] = own[d2];

    // ---- stage fragments: slot s = rep*1024+t -> side|ti|lane ----
    // lane ln: row/col = ti*16 + (ln&15), kg = ln>>4, k = kg*8+e.
    // k0..15 cross: A kg0=hi(-2x) kg1=lo(-2x); B e<4=hi(y) else lo(y).
    // k16..19 norms: (A,B) = (1,y2hi),(1,y2lo),(x2hi,1),(x2lo,1).
    #pragma unroll
    for (int rep = 0; rep < 4; ++rep) {
        const int s    = rep * 1024 + t;
        const int side = s >> 11;
        const int ti   = (s >> 6) & 31;
        const int ln   = s & 63;
        const int row  = ti * 16 + (ln & 15);
        const int kg   = ln >> 4;
        const float* P = side ? kine_pred : kine_input;
        float4 pt = *reinterpret_cast<const float4*>(P + ((size_t)b * NN + row) * 4);
        float n = pt.x*pt.x + pt.y*pt.y + pt.z*pt.z + pt.w*pt.w;
        float w[4];
        if (side == 0) { w[0] = -2.f*pt.x; w[1] = -2.f*pt.y; w[2] = -2.f*pt.z; w[3] = -2.f*pt.w; }
        else           { w[0] =      pt.x; w[1] =      pt.y; w[2] =      pt.z; w[3] =      pt.w; }
        _Float16 hi[4], lo[4];
        #pragma unroll
        for (int c = 0; c < 4; ++c) { hi[c] = (_Float16)w[c]; lo[c] = (_Float16)(w[c] - (float)hi[c]); }
        const _Float16 nhi = (_Float16)n;
        const _Float16 nlo = (_Float16)(n - (float)nhi);
        const _Float16 one = (_Float16)1.f;
        f16x8 hv;
        #pragma unroll
        for (int e = 0; e < 8; ++e) {
            _Float16 v = (_Float16)0.f;
            if (kg < 2) {
                const int c = e & 3;
                if (side == 0) v = (kg == 0) ? hi[c] : lo[c];
                else           v = (e < 4) ? hi[c] : lo[c];
            } else if (kg == 2 && e < 4) {
                if (side == 0) v = (e == 0 || e == 1) ? one : ((e == 2) ? nhi : nlo);
                else           v = (e == 0) ? nhi : ((e == 1) ? nlo : one);
            }
            hv[e] = v;
        }
        (side ? sB : sA)[ti * 64 + ln] = hv;
    }
    __syncthreads();

    // ---- concurrent transposed scans on wave halves ----
    if (wave < 8) min_scan4(sA, sB, part[0], wave,     lane);
    else          min_scan4(sB, sA, part[1], wave - 8, lane);

    // ---- histograms (labels independent of argmins) + KL ----
    {
        const float* cls = (t < NN) ? class_input : class_pred;
        const int r = t & (NN - 1);
        const float* rowp = cls + ((size_t)b * NN + r) * DD;
        float mx = rowp[0]; int lab = 0;
        #pragma unroll
        for (int d2 = 1; d2 < DD; ++d2) { float v = rowp[d2]; if (v > mx) { mx = v; lab = d2; } }  // argmax(exp)==argmax
        atomicAdd((t < NN) ? &hist_in[lab] : &hist_pr[lab], 1);
    }
    if (t < 64) {
        float v = 0.f;
        if (t < LL) {
            float m_ = mu[(size_t)b * LL + t];
            float lv = log_var[(size_t)b * LL + t];
            v = 1.f + lv - m_ * m_ - expf(lv);
        }
        #pragma unroll
        for (int off = 32; off > 0; off >>= 1) v += __shfl_down(v, off, 64);
        if (t == 0) s_kl = -0.5f * v;
    }
    __syncthreads();

    // ---- merge 16 groups + epilogue: thread t -> (pass ep_p, row ep_lr) ----
    // Ascending g with strict float <: (d_trunc, jj, g) lex == (d_trunc, col)
    // lex (col = g + 16*jj, jj-major) -> exact first-index semantics on the
    // 5-bit-truncated distances.
    float partsum;
    {
        const unsigned* pr = part[ep_p][ep_lr];
        unsigned e = pr[0]; int bg = 0;
        #pragma unroll
        for (int g = 1; g < 16; ++g) {
            unsigned v = pr[g];
            if (__uint_as_float(v) < __uint_as_float(e)) { e = v; bg = g; }
        }
        const int   idx  = bg + 16 * (int)(e & 31u);
        const float dmin = fmaxf(__uint_as_float(e & 0xFFFFFFE0u), 0.f);   // clamp commutes with min
        const float* oth = (ep_p ? class_input : class_pred) + ((size_t)b * NN + idx) * DD;
        float dot = 0.f;
        #pragma unroll
        for (int d2 = 0; d2 < DD; ++d2) dot += ownv[d2] * oth[d2];
        partsum = dmin - dot;   // chamfer + (-1)*class dot (W=1)
    }
    #pragma unroll
    for (int off = 32; off > 0; off >>= 1) partsum += __shfl_down(partsum, off, 64);
    if (lane == 0) red[wave] = partsum;
    __syncthreads();

    if (t == 0) {
        float sum = 0.f;
        #pragma unroll
        for (int w2 = 0; w2 < 16; ++w2) sum += red[w2];
        float cnum = 0.f;
        #pragma unroll
        for (int c = 0; c < DD; ++c) {
            float diff = fabsf((float)(hist_pr[c] - hist_in[c]));
            float wgt = (c == 0) ? 2.0f : ((c == DD - 1) ? 100.0f : 1.0f);
            cnum += wgt * diff;
        }
        out[b] = 0.99f * (sum + 0.001f * cnum) + 0.01f * s_kl;
    }
}

extern "C" void kernel_launch(void* const* d_in, const int* in_sizes, int n_in,
                              void* d_out, int out_size, void* d_ws, size_t ws_size,
                              hipStream_t stream) {
    const float* kine_input  = (const float*)d_in[0];
    const float* class_input = (const float*)d_in[1];
    const float* kine_pred   = (const float*)d_in[2];
    const float* class_pred  = (const float*)d_in[3];
    const float* mu          = (const float*)d_in[4];
    const float* log_var     = (const float*)d_in[5];
    float* out = (float*)d_out;

    loss_kernel<<<256, 1024, 0, stream>>>(kine_input, class_input, kine_pred,
                                          class_pred, mu, log_var, out);
}